// Round 5
// baseline (541.952 us; speedup 1.0000x reference)
//
#include <hip/hip_runtime.h>
#include <hip/hip_bf16.h>
#include <math.h>

typedef __attribute__((ext_vector_type(8))) _Float16 f16x8;
typedef __attribute__((ext_vector_type(4))) float f32x4;

static __device__ __forceinline__ float sigmoidf_(float x) {
    return 1.0f / (1.0f + expf(-x));
}

// ---------------------------------------------------------------------------
// fp32 -> fp16 with chunk-XOR pre-swizzle, 3 tensors in one launch.
// Logical chunk src[row][kc] lands at dst[row][kcs], kcs = (kc&~7)|((kc&7)^(row&7)).
// GEMM stages LDS linearly (global_load_lds), ds_read applies the same XOR
// -> conflict-free b128 fragment reads (both-sides rule #21).
// ---------------------------------------------------------------------------
__global__ void cvt_all(const float* __restrict__ s0, _Float16* __restrict__ d0, int n0,
                        const float* __restrict__ s1, _Float16* __restrict__ d1, int n1,
                        const float* __restrict__ s2, _Float16* __restrict__ d2, int n2,
                        int ck01, int ck2)
{
    int c = blockIdx.x * 256 + threadIdx.x;
    const float* s; _Float16* d; int ck;
    if (c < n0)            { s = s0; d = d0; ck = ck01; }
    else if (c < n0 + n1)  { c -= n0; s = s1; d = d1; ck = ck01; }
    else                   { c -= n0 + n1; if (c >= n2) return; s = s2; d = d2; ck = ck2; }
    const int row = c / ck;
    const int kc  = c - row * ck;
    const int kcs = (kc & ~7) | ((kc & 7) ^ (row & 7));
    const float* sp = s + (size_t)c * 8;
    float4 v0 = *(const float4*)sp;
    float4 v1 = *(const float4*)(sp + 4);
    f16x8 h;
    h[0] = (_Float16)v0.x; h[1] = (_Float16)v0.y;
    h[2] = (_Float16)v0.z; h[3] = (_Float16)v0.w;
    h[4] = (_Float16)v1.x; h[5] = (_Float16)v1.y;
    h[6] = (_Float16)v1.z; h[7] = (_Float16)v1.w;
    *(f16x8*)(d + (size_t)row * ((size_t)ck * 8) + (size_t)kcs * 8) = h;
}

// ---------------------------------------------------------------------------
// Single-wave GEMM: block = 64 threads = 1 wave owning a BMxBN output tile.
// No barriers; double-buffered LDS with counted s_waitcnt vmcnt(N) so next
// tile's global_load_lds stay in flight across the MFMA cluster.
// A: [M][K] fp16 pre-swizzled, Bw: [N][K] fp16 pre-swizzled.
// EPI=0: write fp16 C row-major (gi). EPI=1: sigmoid + broadcast x T into out.
// ---------------------------------------------------------------------------
template <int BM, int BN, int EPI>
__launch_bounds__(64, 1)
__global__ void gemm_sw(const _Float16* __restrict__ A, const _Float16* __restrict__ Bw,
                        const float* __restrict__ bias, void* __restrict__ Cv,
                        int N, int K, int T)
{
    constexpr int MR = BM / 16, NR = BN / 16;
    constexpr int NA = BM / 8, NB = BN / 8;      // global_load_lds per tile
    constexpr int NL = NA + NB;

    __shared__ _Float16 As[2][BM * 64];
    __shared__ _Float16 Bs[2][BN * 64];

    const int tid  = threadIdx.x;                 // 0..63
    const int lr   = tid & 15;
    const int kb   = tid >> 4;
    const int brow = blockIdx.y * BM;
    const int bcol = blockIdx.x * BN;

    // staging bases: thread t covers chunk rows (t>>3)+8i, chunk col t&7
    const _Float16* ap = A  + (size_t)(brow + (tid >> 3)) * K + (tid & 7) * 8;
    const _Float16* bp = Bw + (size_t)(bcol + (tid >> 3)) * K + (tid & 7) * 8;

    // fragment-read element offsets (XOR-unswizzle), same for every m/n
    const int eb0 = lr * 64 + (((0 * 4 + kb) ^ (lr & 7)) * 8);
    const int eb1 = lr * 64 + (((1 * 4 + kb) ^ (lr & 7)) * 8);

    f32x4 acc[MR][NR] = {};

    auto stage = [&](int buf, int kt) {
        const _Float16* a = ap + (size_t)kt * 64;
#pragma unroll
        for (int i = 0; i < NA; ++i)
            __builtin_amdgcn_global_load_lds(
                (const __attribute__((address_space(1))) void*)(a + (size_t)i * 8 * K),
                (__attribute__((address_space(3))) void*)&As[buf][(i * 64 + tid) * 8],
                16, 0, 0);
        const _Float16* b = bp + (size_t)kt * 64;
#pragma unroll
        for (int i = 0; i < NB; ++i)
            __builtin_amdgcn_global_load_lds(
                (const __attribute__((address_space(1))) void*)(b + (size_t)i * 8 * K),
                (__attribute__((address_space(3))) void*)&Bs[buf][(i * 64 + tid) * 8],
                16, 0, 0);
    };

    auto compute = [&](int cur) {
        const _Float16* as = &As[cur][0];
        const _Float16* bs = &Bs[cur][0];
        __builtin_amdgcn_s_setprio(1);
#pragma unroll
        for (int ks = 0; ks < 2; ++ks) {
            const int eb = ks ? eb1 : eb0;
            f16x8 af[MR], bf[NR];
#pragma unroll
            for (int m = 0; m < MR; ++m) af[m] = *(const f16x8*)(as + m * 16 * 64 + eb);
#pragma unroll
            for (int n = 0; n < NR; ++n) bf[n] = *(const f16x8*)(bs + n * 16 * 64 + eb);
#pragma unroll
            for (int n = 0; n < NR; ++n)
#pragma unroll
                for (int m = 0; m < MR; ++m)
                    acc[m][n] = __builtin_amdgcn_mfma_f32_16x16x32_f16(af[m], bf[n], acc[m][n], 0, 0, 0);
        }
        __builtin_amdgcn_s_setprio(0);
    };

    const int nt = K / 64;
    stage(0, 0);
    int t = 0;
    for (; t < nt - 1; ++t) {
        stage((t & 1) ^ 1, t + 1);                       // NL loads in flight for t+1
        asm volatile("s_waitcnt vmcnt(%0)" :: "i"(NL) : "memory");  // tile t resident
        __builtin_amdgcn_sched_barrier(0);
        compute(t & 1);
    }
    asm volatile("s_waitcnt vmcnt(0)" ::: "memory");
    __builtin_amdgcn_sched_barrier(0);
    compute(t & 1);

    // C/D mapping (HW-verified rounds 1-2): col = lane&15, row = (lane>>4)*4 + j
    if (EPI == 0) {
        _Float16* C = (_Float16*)Cv;
#pragma unroll
        for (int m = 0; m < MR; ++m) {
            const int r0 = brow + m * 16 + kb * 4;
#pragma unroll
            for (int n = 0; n < NR; ++n) {
                const int col = bcol + n * 16 + lr;
                const float bv = bias[col];
#pragma unroll
                for (int j = 0; j < 4; ++j)
                    C[(size_t)(r0 + j) * N + col] = (_Float16)(acc[m][n][j] + bv);
            }
        }
    } else {
        float* Co = (float*)Cv;
#pragma unroll
        for (int m = 0; m < MR; ++m) {
            const int r0 = brow + m * 16 + kb * 4;
#pragma unroll
            for (int n = 0; n < NR; ++n) {
                const int col = bcol + n * 16 + lr;
                const float bv = bias[col];
#pragma unroll
                for (int j = 0; j < 4; ++j) {
                    const float v = sigmoidf_(acc[m][n][j] + bv);
                    const size_t base = ((size_t)(r0 + j) * N + col) * (size_t)T;
                    if (!(T & 1)) {
                        float2* o2 = (float2*)(Co + base);
                        const float2 vv = make_float2(v, v);
                        for (int p = 0; p < T / 2; ++p) o2[p] = vv;
                    } else {
                        for (int p = 0; p < T; ++p) Co[base + p] = v;
                    }
                }
            }
        }
    }
}

// ---------------------------------------------------------------------------
// GRU gate with h=0 (w_hh dead): reads fp16 gi, writes h_new fp16 in the
// chunk-XOR swizzled layout (row = batch) for GEMM2's A staging.
// ---------------------------------------------------------------------------
__global__ void gate_swz(const _Float16* __restrict__ gi, const float* __restrict__ b_hh,
                         _Float16* __restrict__ hn, int B, int H)
{
    const int ch = H >> 3;
    const int c = blockIdx.x * 256 + threadIdx.x;
    if (c >= B * ch) return;
    const int b  = c / ch;
    const int hc = c - b * ch;
    const int h0 = hc * 8;
    const _Float16* g = gi + (size_t)b * 3 * H + h0;
    f16x8 ir = *(const f16x8*)g;
    f16x8 iz = *(const f16x8*)(g + H);
    f16x8 in = *(const f16x8*)(g + 2 * H);
    float hr[8], hz[8], hnn[8];
    *(float4*)&hr[0]  = *(const float4*)(b_hh + h0);
    *(float4*)&hr[4]  = *(const float4*)(b_hh + h0 + 4);
    *(float4*)&hz[0]  = *(const float4*)(b_hh + H + h0);
    *(float4*)&hz[4]  = *(const float4*)(b_hh + H + h0 + 4);
    *(float4*)&hnn[0] = *(const float4*)(b_hh + 2 * H + h0);
    *(float4*)&hnn[4] = *(const float4*)(b_hh + 2 * H + h0 + 4);
    f16x8 o;
#pragma unroll
    for (int q = 0; q < 8; ++q) {
        const float r = sigmoidf_((float)ir[q] + hr[q]);
        const float z = sigmoidf_((float)iz[q] + hz[q]);
        o[q] = (_Float16)((1.0f - z) * tanhf((float)in[q] + r * hnn[q]));
    }
    const int hcs = (hc & ~7) | ((hc & 7) ^ (b & 7));
    *(f16x8*)(hn + (size_t)b * H + (size_t)hcs * 8) = o;
}

extern "C" void kernel_launch(void* const* d_in, const int* in_sizes, int n_in,
                              void* d_out, int out_size, void* d_ws, size_t ws_size,
                              hipStream_t stream)
{
    const float* x     = (const float*)d_in[0];
    const float* w_ih  = (const float*)d_in[1];
    // d_in[2] = w_hh: dead (hidden state stays 0)
    const float* b_ih  = (const float*)d_in[3];
    const float* b_hh  = (const float*)d_in[4];
    const float* w_cls = (const float*)d_in[5];
    const float* b_cls = (const float*)d_in[6];

    const int H3 = in_sizes[3];          // 6144
    const int H  = H3 / 3;               // 2048
    const int I  = in_sizes[1] / H3;     // 2048
    const int B  = in_sizes[0] / I;      // 1024
    const int O  = in_sizes[6];          // 2048
    const int T  = out_size / (B * O);   // 30

    // ws: x16 | wcls16 | hn16  (16.8 MB)
    _Float16* x16    = (_Float16*)d_ws;
    _Float16* wcls16 = x16 + (size_t)B * I;
    _Float16* hn16   = wcls16 + (size_t)O * H;

    // d_out doubles as scratch (proven safe round 2): wih16 | gi16 (36 MB),
    // both fully consumed before the fused GEMM2 epilogue overwrites d_out.
    _Float16* wih16 = (_Float16*)d_out;
    _Float16* gi16  = wih16 + (size_t)H3 * I;

    dim3 blk(256);

    // one launch: fp32 -> fp16 pre-swizzled for x, w_ih, w_cls
    {
        const int n0 = B * I / 8, n1 = H3 * I / 8, n2 = O * H / 8;
        const int tot = n0 + n1 + n2;
        cvt_all<<<(tot + 255) / 256, blk, 0, stream>>>(x, x16, n0, w_ih, wih16, n1,
                                                       w_cls, wcls16, n2, I / 8, H / 8);
    }

    // GEMM1: gi16 = fp16(x @ w_ih^T + b_ih). 48x16 = 768 single-wave blocks (3/CU).
    gemm_sw<64, 128, 0><<<dim3(H3 / 128, B / 64), dim3(64), 0, stream>>>(
        x16, wih16, b_ih, gi16, H3, I, 0);

    // gate -> h_new (fp16, swizzled)
    gate_swz<<<(B * H / 8 + 255) / 256, blk, 0, stream>>>(gi16, b_hh, hn16, B, H);

    // GEMM2 + fused broadcast: out[b][o][0..T) = sigmoid(h_new @ w_cls^T + b_cls).
    // 32x16 = 512 single-wave blocks (2/CU); epilogue streams 252 MB.
    gemm_sw<64, 64, 1><<<dim3(O / 64, B / 64), dim3(64), 0, stream>>>(
        hn16, wcls16, b_cls, d_out, O, H, T);
}

// Round 8
// 411.016 us; speedup vs baseline: 1.3186x; 1.3186x over previous
//
#include <hip/hip_runtime.h>
#include <hip/hip_bf16.h>
#include <math.h>

typedef __attribute__((ext_vector_type(8))) _Float16 f16x8;
typedef __attribute__((ext_vector_type(4))) float f32x4;

static __device__ __forceinline__ float sigmoidf_(float x) {
    return 1.0f / (1.0f + expf(-x));
}

// ---------------------------------------------------------------------------
// fp32 -> fp16 with chunk-XOR pre-swizzle, 3 tensors in one launch.
// Logical chunk src[row][kc] lands at dst[row][kcs], kcs = (kc&~7)|((kc&7)^(row&7)).
// GEMM stages LDS linearly (global_load_lds), ds_read applies the same XOR
// -> conflict-free b128 fragment reads (verified: SQ_LDS_BANK_CONFLICT = 0).
// ---------------------------------------------------------------------------
__global__ void cvt_all(const float* __restrict__ s0, _Float16* __restrict__ d0, int n0,
                        const float* __restrict__ s1, _Float16* __restrict__ d1, int n1,
                        const float* __restrict__ s2, _Float16* __restrict__ d2, int n2,
                        int ck01, int ck2)
{
    int c = blockIdx.x * 256 + threadIdx.x;
    const float* s; _Float16* d; int ck;
    if (c < n0)            { s = s0; d = d0; ck = ck01; }
    else if (c < n0 + n1)  { c -= n0; s = s1; d = d1; ck = ck01; }
    else                   { c -= n0 + n1; if (c >= n2) return; s = s2; d = d2; ck = ck2; }
    const int row = c / ck;
    const int kc  = c - row * ck;
    const int kcs = (kc & ~7) | ((kc & 7) ^ (row & 7));
    const float* sp = s + (size_t)c * 8;
    float4 v0 = *(const float4*)sp;
    float4 v1 = *(const float4*)(sp + 4);
    f16x8 h;
    h[0] = (_Float16)v0.x; h[1] = (_Float16)v0.y;
    h[2] = (_Float16)v0.z; h[3] = (_Float16)v0.w;
    h[4] = (_Float16)v1.x; h[5] = (_Float16)v1.y;
    h[6] = (_Float16)v1.z; h[7] = (_Float16)v1.w;
    *(f16x8*)(d + (size_t)row * ((size_t)ck * 8) + (size_t)kcs * 8) = h;
}

// ---------------------------------------------------------------------------
// Multi-wave GEMM (m97 structure): 256 threads = 4 waves in a 2x2 grid, each
// wave owns a (BM/2)x(BN/2) quadrant. 2 barriers per K-step, single LDS
// buffer, global_load_lds width-16 staging of pre-swizzled fp16 operands.
// C[m][n] = sum_k A[m][k]*Bw[n][k] + bias[n].
// EPI=0: write fp16 C row-major (gi). EPI=1: sigmoid, write fp32 (res).
// ---------------------------------------------------------------------------
template <int BM, int BN, int EPI>
__launch_bounds__(256, 2)
__global__ void gemm_mw(const _Float16* __restrict__ A, const _Float16* __restrict__ Bw,
                        const float* __restrict__ bias, void* __restrict__ Cv,
                        int N, int K)
{
    constexpr int BK = 64;
    constexpr int WM = BM / 2, WN = BN / 2;
    constexpr int MR = WM / 16, NR = WN / 16;

    __shared__ _Float16 As[BM * BK];
    __shared__ _Float16 Bs[BN * BK];

    const int tid  = threadIdx.x;
    const int lane = tid & 63;
    const int wid  = tid >> 6;
    const int wr   = wid >> 1;       // wave row 0..1
    const int wc   = wid & 1;        // wave col 0..1
    const int brow = blockIdx.y * BM;
    const int bcol = blockIdx.x * BN;
    const int lr   = lane & 15;
    const int kb   = lane >> 4;      // 0..3

    // staging: thread t covers global chunk rows (t>>3)+32i, chunk col t&7
    const _Float16* ap = A  + (size_t)(brow + (tid >> 3)) * K + (tid & 7) * 8;
    const _Float16* bp = Bw + (size_t)(bcol + (tid >> 3)) * K + (tid & 7) * 8;

    f32x4 acc[MR][NR] = {};

    for (int k0 = 0; k0 < K; k0 += BK) {
        __syncthreads();
#pragma unroll
        for (int c0 = 0; c0 < BM * 8; c0 += 256)
            __builtin_amdgcn_global_load_lds(
                (const __attribute__((address_space(1))) void*)(ap + k0 + (size_t)(c0 >> 3) * K),
                (__attribute__((address_space(3))) void*)&As[(c0 + tid) * 8],
                16, 0, 0);
#pragma unroll
        for (int c0 = 0; c0 < BN * 8; c0 += 256)
            __builtin_amdgcn_global_load_lds(
                (const __attribute__((address_space(1))) void*)(bp + k0 + (size_t)(c0 >> 3) * K),
                (__attribute__((address_space(3))) void*)&Bs[(c0 + tid) * 8],
                16, 0, 0);
        __syncthreads();   // compiler drains vmcnt(0) here (m97-structure stall, accepted)

#pragma unroll
        for (int ks = 0; ks < 2; ++ks) {
            f16x8 af[MR], bf[NR];
#pragma unroll
            for (int m = 0; m < MR; ++m) {
                const int row = wr * WM + m * 16 + lr;
                af[m] = *(const f16x8*)&As[row * BK + ((ks * 4 + kb) ^ (row & 7)) * 8];
            }
#pragma unroll
            for (int n = 0; n < NR; ++n) {
                const int row = wc * WN + n * 16 + lr;
                bf[n] = *(const f16x8*)&Bs[row * BK + ((ks * 4 + kb) ^ (row & 7)) * 8];
            }
#pragma unroll
            for (int n = 0; n < NR; ++n)
#pragma unroll
                for (int m = 0; m < MR; ++m)
                    acc[m][n] = __builtin_amdgcn_mfma_f32_16x16x32_f16(af[m], bf[n], acc[m][n], 0, 0, 0);
        }
    }

    // C/D mapping (HW-verified): col = lane&15, row = (lane>>4)*4 + j
#pragma unroll
    for (int m = 0; m < MR; ++m) {
        const int r0 = brow + wr * WM + m * 16 + kb * 4;
#pragma unroll
        for (int n = 0; n < NR; ++n) {
            const int col = bcol + wc * WN + n * 16 + lr;
            const float bv = bias[col];
#pragma unroll
            for (int j = 0; j < 4; ++j) {
                const float v = acc[m][n][j] + bv;
                if (EPI == 0)
                    ((_Float16*)Cv)[(size_t)(r0 + j) * N + col] = (_Float16)v;
                else
                    ((float*)Cv)[(size_t)(r0 + j) * N + col] = sigmoidf_(v);
            }
        }
    }
}

// ---------------------------------------------------------------------------
// GRU gate with h=0 (w_hh dead): reads fp16 gi, writes h_new fp16 in the
// chunk-XOR swizzled layout (row = batch) for GEMM2's A staging.
// ---------------------------------------------------------------------------
__global__ void gate_swz(const _Float16* __restrict__ gi, const float* __restrict__ b_hh,
                         _Float16* __restrict__ hn, int B, int H)
{
    const int ch = H >> 3;
    const int c = blockIdx.x * 256 + threadIdx.x;
    if (c >= B * ch) return;
    const int b  = c / ch;
    const int hc = c - b * ch;
    const int h0 = hc * 8;
    const _Float16* g = gi + (size_t)b * 3 * H + h0;
    f16x8 ir = *(const f16x8*)g;
    f16x8 iz = *(const f16x8*)(g + H);
    f16x8 in = *(const f16x8*)(g + 2 * H);
    float hr[8], hz[8], hnn[8];
    *(float4*)&hr[0]  = *(const float4*)(b_hh + h0);
    *(float4*)&hr[4]  = *(const float4*)(b_hh + h0 + 4);
    *(float4*)&hz[0]  = *(const float4*)(b_hh + H + h0);
    *(float4*)&hz[4]  = *(const float4*)(b_hh + H + h0 + 4);
    *(float4*)&hnn[0] = *(const float4*)(b_hh + 2 * H + h0);
    *(float4*)&hnn[4] = *(const float4*)(b_hh + 2 * H + h0 + 4);
    f16x8 o;
#pragma unroll
    for (int q = 0; q < 8; ++q) {
        const float r = sigmoidf_((float)ir[q] + hr[q]);
        const float z = sigmoidf_((float)iz[q] + hz[q]);
        o[q] = (_Float16)((1.0f - z) * tanhf((float)in[q] + r * hnn[q]));
    }
    const int hcs = (hc & ~7) | ((hc & 7) ^ (b & 7));
    *(f16x8*)(hn + (size_t)b * H + (size_t)hcs * 8) = o;
}

// out[b][o][t] = res[b][o]; 256-thread blocks, lane-adjacent float2 stores
// (proven >6 TB/s in round 2; the fused variant ran at 1.5 TB/s -> reverted).
__global__ void bcast_kernel(const float* __restrict__ res,
                             float* __restrict__ out, int BO, int T)
{
    const int bo0 = blockIdx.x * 256;
    if (T & 1) {
        float* op = out + (size_t)bo0 * T;
        const int n = 256 * T;
        for (int j = threadIdx.x; j < n; j += blockDim.x)
            op[j] = res[bo0 + j / T];
    } else {
        const int half = T >> 1;
        float2* o2 = (float2*)(out + (size_t)bo0 * T);
        const int n2 = 256 * half;
        for (int j = threadIdx.x; j < n2; j += blockDim.x) {
            const float v = res[bo0 + j / half];
            o2[j] = make_float2(v, v);
        }
    }
}

extern "C" void kernel_launch(void* const* d_in, const int* in_sizes, int n_in,
                              void* d_out, int out_size, void* d_ws, size_t ws_size,
                              hipStream_t stream)
{
    const float* x     = (const float*)d_in[0];
    const float* w_ih  = (const float*)d_in[1];
    // d_in[2] = w_hh: dead (hidden state stays 0)
    const float* b_ih  = (const float*)d_in[3];
    const float* b_hh  = (const float*)d_in[4];
    const float* w_cls = (const float*)d_in[5];
    const float* b_cls = (const float*)d_in[6];

    const int H3 = in_sizes[3];          // 6144
    const int H  = H3 / 3;               // 2048
    const int I  = in_sizes[1] / H3;     // 2048
    const int B  = in_sizes[0] / I;      // 1024
    const int O  = in_sizes[6];          // 2048
    const int T  = out_size / (B * O);   // 30

    // ws (24.9 MB): x16 | wcls16 | hn16 | res
    _Float16* x16    = (_Float16*)d_ws;                 // B*I fp16
    _Float16* wcls16 = x16 + (size_t)B * I;             // O*H fp16
    _Float16* hn16   = wcls16 + (size_t)O * H;          // B*H fp16
    float*    res    = (float*)(hn16 + (size_t)B * H);  // B*O fp32

    // d_out doubles as scratch (proven safe rounds 2/5): wih16 | gi16 (37.8 MB),
    // both fully consumed before bcast overwrites the whole output buffer.
    _Float16* wih16 = (_Float16*)d_out;
    _Float16* gi16  = wih16 + (size_t)H3 * I;

    dim3 blk(256);

    // fp32 -> fp16 pre-swizzled: x, w_ih, w_cls in one launch
    {
        const int n0 = B * I / 8, n1 = H3 * I / 8, n2 = O * H / 8;
        const int tot = n0 + n1 + n2;
        cvt_all<<<(tot + 255) / 256, blk, 0, stream>>>(x, x16, n0, w_ih, wih16, n1,
                                                       w_cls, wcls16, n2, I / 8, H / 8);
    }

    // GEMM1: gi16 = fp16(x @ w_ih^T + b_ih). 128x96 tiles -> (64,8) = 512 blocks
    // = exactly 2/CU resident (8 waves/CU), no tail imbalance.
    gemm_mw<128, 96, 0><<<dim3(H3 / 96, B / 128), blk, 0, stream>>>(
        x16, wih16, b_ih, gi16, H3, I);

    // gate -> h_new (fp16, swizzled)
    gate_swz<<<(B * H / 8 + 255) / 256, blk, 0, stream>>>(gi16, b_hh, hn16, B, H);

    // GEMM2: res = sigmoid(h_new @ w_cls^T + b_cls). 64x64 -> (32,16) = 512 blocks = 2/CU.
    gemm_mw<64, 64, 1><<<dim3(O / 64, B / 64), blk, 0, stream>>>(
        hn16, wcls16, b_cls, res, O, H);

    // broadcast across T (separate, coalesced)
    bcast_kernel<<<(B * O) / 256, blk, 0, stream>>>(res, (float*)d_out, B * O, T);
}